// Round 7
// baseline (460.649 us; speedup 1.0000x reference)
//
#include <hip/hip_runtime.h>

// Problem constants (fixed by the reference harness).
constexpr int Nn   = 100000;   // nodes
constexpr int Ee   = 1600000;  // edges  (divisible by 4)
constexpr int D    = 128;      // feature dim
constexpr int NT   = 18;       // 2 + 16 target entries (duplicates allowed)
constexpr int NB   = 256;      // grid blocks (1 per CU -> co-residency guaranteed)

// Capacities (expected: |L2|~290, |S|~330, |L1|~5000)
constexpr int CAPS = 1024;
constexpr int CAP2 = 1024;
constexpr int CAP1 = 8192;

constexpr int BMW = 3136;      // bitmap words: >= ceil(Nn/32)=3125, %4==0
constexpr int LOC = 128;       // per-block LDS staging capacity (edge hits)
constexpr int LOCC= 384;       // per-block staging for stageC node hits

// hdr slots
#define HDR_CNTS  1
#define HDR_CNTL1 2
#define HDR_CNTL2 3

// ---- workspace byte offsets (all 16B aligned) ----
constexpr size_t OFF_HDR   = 0;          // int[64]          256   (zeroed in P0)
constexpr size_t OFF_MARKS = 256;        // int[Nn]          400000
constexpr size_t OFF_BMS   = 400256;     // u32[BMW]         12544
constexpr size_t OFF_A1    = 412800;     // f32[CAPS*D]      524288
constexpr size_t OFF_A2    = 937088;     // f32[32*D]        16384
constexpr size_t ZERO_BYTES= 953472;     // kernel P0 zeroes [0, ZERO_BYTES)
constexpr size_t OFF_BAR   = 953472;     // int[64]          256  (host memset)
constexpr size_t OFF_SLIST = 953728;     // int[CAPS]        4096
constexpr size_t OFF_L2    = 957824;     // int[CAP2*3]      12288
constexpr size_t OFF_L1    = 970112;     // int[CAP1*3]      98304
constexpr size_t OFF_HS    = 1068416;    // f32[CAPS*D]      524288
constexpr size_t OFF_EMB   = 1592704;    // f32[32*D]        16384
constexpr size_t WS_NEED   = 1608960;

// Device-scope sense-reversing grid barrier. All NB blocks are co-resident
// (NB = #CUs, tiny LDS/VGPR footprint), so spinning is safe. Per-thread
// agent fence + block barrier, then thread 0 does the agent-scope
// release-arrive / acquire-wait (the cooperative-groups lowering pattern).
__device__ __forceinline__ void gbar(int* bar) {
    __threadfence();
    __syncthreads();
    if (threadIdx.x == 0) {
        int g = __hip_atomic_load(&bar[1], __ATOMIC_RELAXED, __HIP_MEMORY_SCOPE_AGENT);
        int prev = __hip_atomic_fetch_add(&bar[0], 1, __ATOMIC_ACQ_REL, __HIP_MEMORY_SCOPE_AGENT);
        if (prev == NB - 1) {
            __hip_atomic_store(&bar[0], 0, __ATOMIC_RELAXED, __HIP_MEMORY_SCOPE_AGENT);
            __hip_atomic_fetch_add(&bar[1], 1, __ATOMIC_ACQ_REL, __HIP_MEMORY_SCOPE_AGENT);
        } else {
            while (__hip_atomic_load(&bar[1], __ATOMIC_ACQUIRE, __HIP_MEMORY_SCOPE_AGENT) == g)
                __builtin_amdgcn_s_sleep(2);
        }
    }
    __syncthreads();
}

union Smem {
    struct { unsigned bm[BMW]; int sT[NT]; int loc[LOCC * 3]; } scan;
    struct { float buf[D]; float hid[D]; int sT[NT]; } mlp;
    struct { float cat[3 * D]; float part[2][D]; float red[D]; int sT[NT]; } pol;
};

__global__ void __launch_bounds__(256)
k_mega(const float* __restrict__ x, const int* __restrict__ src,
       const int* __restrict__ dst,
       const int* __restrict__ cur, const int* __restrict__ des,
       const int* __restrict__ nbr, const float* __restrict__ ea,
       const float* __restrict__ We1, const float* __restrict__ be1,
       const float* __restrict__ W11, const float* __restrict__ b11,
       const float* __restrict__ W12, const float* __restrict__ b12,
       const float* __restrict__ We2, const float* __restrict__ be2,
       const float* __restrict__ W21, const float* __restrict__ b21,
       const float* __restrict__ W22, const float* __restrict__ b22,
       const float* __restrict__ Wl1, const float* __restrict__ bl1,
       const float* __restrict__ Wl2, const float* __restrict__ bl2,
       char* __restrict__ ws, float* __restrict__ out) {
    __shared__ Smem sm;
    __shared__ int lcnt, lbase;

    int*      hdr   = (int*)(ws + OFF_HDR);
    int*      markS = (int*)(ws + OFF_MARKS);
    unsigned* bmS   = (unsigned*)(ws + OFF_BMS);
    float*    A1    = (float*)(ws + OFF_A1);
    float*    A2    = (float*)(ws + OFF_A2);
    int*      bar   = (int*)(ws + OFF_BAR);
    int*      Slist = (int*)(ws + OFF_SLIST);
    int*      L2    = (int*)(ws + OFF_L2);
    int*      L1    = (int*)(ws + OFF_L1);
    float*    Hs    = (float*)(ws + OFF_HS);
    float*    EMB   = (float*)(ws + OFF_EMB);

    const int t    = threadIdx.x;
    const int b    = blockIdx.x;
    const int gtid = b * 256 + t;

    // ---------------- P0: zero hdr/markS/bmS/A1/A2 ----------------
    {
        float4* p = (float4*)ws;
        for (int i = gtid; i < (int)(ZERO_BYTES / 16); i += NB * 256)
            p[i] = float4{0.f, 0.f, 0.f, 0.f};
    }
    gbar(bar);

    // ---------------- P1: scanT (edges with dst in target set) ----------------
    {
        for (int w = t; w < BMW; w += 256) sm.scan.bm[w] = 0u;
        if (t < NT)
            sm.scan.sT[t] = (t == 0) ? cur[0] : (t == 1) ? des[0] : nbr[t - 2];
        if (t == 0) lcnt = 0;
        __syncthreads();
        if (t < NT) {
            int v = sm.scan.sT[t];
            atomicOr(&sm.scan.bm[(unsigned)v >> 5], 1u << (v & 31));
            if (b == 0) markS[v] = 1;   // targets need h too
        }
        __syncthreads();
        for (int q = gtid; q < Ee / 4; q += NB * 256) {
            int4 d4 = reinterpret_cast<const int4*>(dst)[q];
            int dsv[4] = {d4.x, d4.y, d4.z, d4.w};
            #pragma unroll
            for (int j = 0; j < 4; ++j) {
                int d = dsv[j];
                if ((sm.scan.bm[(unsigned)d >> 5] >> (d & 31)) & 1u) {
                    int slot = 0;
                    while (sm.scan.sT[slot] != d) ++slot;  // first occurrence
                    int e = q * 4 + j;
                    int s = src[e];
                    markS[s] = 1;  // benign same-value race
                    int li = atomicAdd(&lcnt, 1);
                    if (li < LOC) {
                        sm.scan.loc[3*li] = s; sm.scan.loc[3*li+1] = e; sm.scan.loc[3*li+2] = slot;
                    } else {  // overflow fallback (statistically never)
                        int idx = atomicAdd(&hdr[HDR_CNTL2], 1);
                        if (idx < CAP2) { L2[3*idx] = s; L2[3*idx+1] = e; L2[3*idx+2] = slot; }
                    }
                }
            }
        }
        __syncthreads();
        if (t == 0) {
            int n = lcnt < LOC ? lcnt : LOC;
            lcnt = n;
            if (n) lbase = atomicAdd(&hdr[HDR_CNTL2], n);
        }
        __syncthreads();
        for (int i = t; i < lcnt; i += 256) {
            int idx = lbase + i;
            if (idx < CAP2) {
                L2[3*idx] = sm.scan.loc[3*i]; L2[3*idx+1] = sm.scan.loc[3*i+1];
                L2[3*idx+2] = sm.scan.loc[3*i+2];
            }
        }
    }
    gbar(bar);

    // ---------------- P2: compact S slots + build S-bitmap ----------------
    {
        if (t == 0) lcnt = 0;
        __syncthreads();
        for (int i = gtid; i < Nn / 4; i += NB * 256) {
            int4 m4 = reinterpret_cast<const int4*>(markS)[i];
            int ms[4] = {m4.x, m4.y, m4.z, m4.w};
            int v0 = i * 4;
            #pragma unroll
            for (int j = 0; j < 4; ++j) {
                if (ms[j] == 1) {
                    int li = atomicAdd(&lcnt, 1);
                    if (li < LOCC) sm.scan.loc[li] = v0 + j;
                    else {  // overflow fallback
                        int s = atomicAdd(&hdr[HDR_CNTS], 1);
                        if (s < CAPS) {
                            int v = v0 + j;
                            markS[v] = 2 + s; Slist[s] = v;
                            atomicOr(&bmS[(unsigned)v >> 5], 1u << (v & 31));
                        }
                    }
                }
            }
        }
        __syncthreads();
        if (t == 0) {
            int n = lcnt < LOCC ? lcnt : LOCC;
            lcnt = n;
            if (n) lbase = atomicAdd(&hdr[HDR_CNTS], n);
        }
        __syncthreads();
        for (int i = t; i < lcnt; i += 256) {
            int s = lbase + i;
            if (s < CAPS) {
                int v = sm.scan.loc[i];
                markS[v] = 2 + s;
                Slist[s] = v;
                atomicOr(&bmS[(unsigned)v >> 5], 1u << (v & 31));
            }
        }
    }
    gbar(bar);

    // ---------------- P3: scanS (edges with dst in S) ----------------
    {
        if (t == 0) lcnt = 0;
        const uint4* g4 = reinterpret_cast<const uint4*>(bmS);
        for (int w = t; w < BMW / 4; w += 256)
            reinterpret_cast<uint4*>(sm.scan.bm)[w] = g4[w];
        __syncthreads();
        for (int q = gtid; q < Ee / 4; q += NB * 256) {
            int4 d4 = reinterpret_cast<const int4*>(dst)[q];
            int dsv[4] = {d4.x, d4.y, d4.z, d4.w};
            #pragma unroll
            for (int j = 0; j < 4; ++j) {
                int d = dsv[j];
                if ((sm.scan.bm[(unsigned)d >> 5] >> (d & 31)) & 1u) {
                    int e = q * 4 + j;
                    int v = markS[d];
                    if (v >= 2) {
                        int li = atomicAdd(&lcnt, 1);
                        if (li < LOC) {
                            sm.scan.loc[3*li] = src[e]; sm.scan.loc[3*li+1] = e;
                            sm.scan.loc[3*li+2] = v - 2;
                        } else {  // overflow fallback
                            int idx = atomicAdd(&hdr[HDR_CNTL1], 1);
                            if (idx < CAP1) { L1[3*idx] = src[e]; L1[3*idx+1] = e; L1[3*idx+2] = v - 2; }
                        }
                    }
                }
            }
        }
        __syncthreads();
        if (t == 0) {
            int n = lcnt < LOC ? lcnt : LOC;
            lcnt = n;
            if (n) lbase = atomicAdd(&hdr[HDR_CNTL1], n);
        }
        __syncthreads();
        for (int i = t; i < lcnt; i += 256) {
            int idx = lbase + i;
            if (idx < CAP1) {
                L1[3*idx] = sm.scan.loc[3*i]; L1[3*idx+1] = sm.scan.loc[3*i+1];
                L1[3*idx+2] = sm.scan.loc[3*i+2];
            }
        }
    }
    gbar(bar);

    // ---------------- P4: aggregate conv1 messages into A1 ----------------
    {
        int cnt = hdr[HDR_CNTL1]; if (cnt > CAP1) cnt = CAP1;
        int g  = t >> 5;
        int d0 = (t & 31) << 2;
        for (int i = b * 8 + g; i < cnt; i += NB * 8) {
            int s = L1[3*i], e = L1[3*i+1], slot = L1[3*i+2];
            float a = ea[e];
            float4 xv = *reinterpret_cast<const float4*>(&x[(size_t)s * D + d0]);
            float4 wv = *reinterpret_cast<const float4*>(&We1[d0]);
            float4 bv = *reinterpret_cast<const float4*>(&be1[d0]);
            float* Ar = &A1[(size_t)slot * D + d0];
            atomicAdd(Ar + 0, fmaxf(fmaf(a, wv.x, bv.x) + xv.x, 0.f));
            atomicAdd(Ar + 1, fmaxf(fmaf(a, wv.y, bv.y) + xv.y, 0.f));
            atomicAdd(Ar + 2, fmaxf(fmaf(a, wv.z, bv.z) + xv.z, 0.f));
            atomicAdd(Ar + 3, fmaxf(fmaf(a, wv.w, bv.w) + xv.w, 0.f));
        }
    }
    gbar(bar);

    // ---------------- P5: conv1 MLP per S-node -> Hs ----------------
    {
        int cnt = hdr[HDR_CNTS]; if (cnt > CAPS) cnt = CAPS;
        for (int bb = b; bb < cnt; bb += NB) {
            int node = Slist[bb];
            if (t < D) sm.mlp.buf[t] = x[(size_t)node * D + t] + A1[(size_t)bb * D + t];
            __syncthreads();
            if (t < D) {
                float acc = b11[t];
                #pragma unroll 8
                for (int k = 0; k < D; ++k) acc = fmaf(sm.mlp.buf[k], W11[k * D + t], acc);
                sm.mlp.hid[t] = fmaxf(acc, 0.f);
            }
            __syncthreads();
            if (t < D) {
                float acc2 = b12[t];
                #pragma unroll 8
                for (int k = 0; k < D; ++k) acc2 = fmaf(sm.mlp.hid[k], W12[k * D + t], acc2);
                Hs[(size_t)bb * D + t] = fmaxf(acc2, 0.f);
            }
            __syncthreads();
        }
    }
    gbar(bar);

    // ---------------- P6: aggregate conv2 messages into A2 ----------------
    {
        int cnt = hdr[HDR_CNTL2]; if (cnt > CAP2) cnt = CAP2;
        int g  = t >> 5;
        int d0 = (t & 31) << 2;
        for (int i = b * 8 + g; i < cnt; i += NB * 8) {
            int s = L2[3*i], e = L2[3*i+1], slot = L2[3*i+2];
            int ss = markS[s] - 2;
            if ((unsigned)ss < (unsigned)CAPS) {
                float a = ea[e];
                float4 xv = *reinterpret_cast<const float4*>(&Hs[(size_t)ss * D + d0]);
                float4 wv = *reinterpret_cast<const float4*>(&We2[d0]);
                float4 bv = *reinterpret_cast<const float4*>(&be2[d0]);
                float* Ar = &A2[(size_t)slot * D + d0];
                atomicAdd(Ar + 0, fmaxf(fmaf(a, wv.x, bv.x) + xv.x, 0.f));
                atomicAdd(Ar + 1, fmaxf(fmaf(a, wv.y, bv.y) + xv.y, 0.f));
                atomicAdd(Ar + 2, fmaxf(fmaf(a, wv.z, bv.z) + xv.z, 0.f));
                atomicAdd(Ar + 3, fmaxf(fmaf(a, wv.w, bv.w) + xv.w, 0.f));
            }
        }
    }
    gbar(bar);

    // ---------------- P7: conv2 MLP per target entry -> EMB ----------------
    {
        if (t < NT) sm.mlp.sT[t] = (t == 0) ? cur[0] : (t == 1) ? des[0] : nbr[t - 2];
        __syncthreads();
        bool act = (b < NT);
        int node = -1, ss = -1;
        if (act) {
            node = sm.mlp.sT[b];
            for (int j = 0; j < b; ++j) if (sm.mlp.sT[j] == node) act = false;  // dup
        }
        if (act) {
            ss = markS[node] - 2;
            if ((unsigned)ss >= (unsigned)CAPS) act = false;
        }
        if (act && t < D) sm.mlp.buf[t] = Hs[(size_t)ss * D + t] + A2[(size_t)b * D + t];
        __syncthreads();
        if (act && t < D) {
            float acc = b21[t];
            #pragma unroll 8
            for (int k = 0; k < D; ++k) acc = fmaf(sm.mlp.buf[k], W21[k * D + t], acc);
            sm.mlp.hid[t] = fmaxf(acc, 0.f);
        }
        __syncthreads();
        if (act && t < D) {
            float acc2 = b22[t];
            #pragma unroll 8
            for (int k = 0; k < D; ++k) acc2 = fmaf(sm.mlp.hid[k], W22[k * D + t], acc2);
            EMB[(size_t)b * D + t] = acc2;  // no final relu
        }
    }
    gbar(bar);

    // ---------------- P8: policy head -> out[16] ----------------
    if (b < 16) {
        if (t < NT) sm.pol.sT[t] = (t == 0) ? cur[0] : (t == 1) ? des[0] : nbr[t - 2];
        __syncthreads();
        // first-occurrence slots (must match P1/P7 semantics)
        int dsl = (sm.pol.sT[1] == sm.pol.sT[0]) ? 0 : 1;
        int nn = sm.pol.sT[2 + b];
        int nsl = 2 + b;
        for (int j = 0; j < 2 + b; ++j) if (sm.pol.sT[j] == nn) { nsl = j; break; }
        for (int i = t; i < 3 * D; i += 256) {
            int seg = i >> 7;           // 0=curr, 1=dest, 2=nbr
            int tt = i & (D - 1);
            int slot = (seg == 0) ? 0 : (seg == 1) ? dsl : nsl;
            sm.pol.cat[i] = EMB[slot * D + tt];
        }
        __syncthreads();
        int h  = t >> 7;                // 0..1 -> K-halves of 192
        int tt = t & (D - 1);
        float acc = 0.f;
        int c0 = h * 192;
        #pragma unroll 8
        for (int c = c0; c < c0 + 192; ++c)
            acc = fmaf(sm.pol.cat[c], Wl1[c * D + tt], acc);
        sm.pol.part[h][tt] = acc;
        __syncthreads();
        if (t < D) {
            float v = sm.pol.part[0][t] + sm.pol.part[1][t] + bl1[t];
            sm.pol.red[t] = fmaxf(v, 0.f) * Wl2[t];
        }
        __syncthreads();
        for (int s = 64; s > 0; s >>= 1) {
            if (t < s) sm.pol.red[t] += sm.pol.red[t + s];
            __syncthreads();
        }
        if (t == 0) out[b] = sm.pol.red[0] + bl2[0];
    }
}

extern "C" void kernel_launch(void* const* d_in, const int* in_sizes, int n_in,
                              void* d_out, int out_size, void* d_ws, size_t ws_size,
                              hipStream_t stream) {
    if (ws_size < WS_NEED) return;  // safety guard

    const float* x   = (const float*)d_in[0];
    const int*   ei  = (const int*)d_in[1];   // (2,E) row-major int32
    const int*   cur = (const int*)d_in[2];
    const int*   des = (const int*)d_in[3];
    const int*   nbr = (const int*)d_in[4];
    const float* ea  = (const float*)d_in[5]; // (E,1)
    const float* We1 = (const float*)d_in[6];
    const float* be1 = (const float*)d_in[7];
    const float* W11 = (const float*)d_in[8];
    const float* b11 = (const float*)d_in[9];
    const float* W12 = (const float*)d_in[10];
    const float* b12 = (const float*)d_in[11];
    const float* We2 = (const float*)d_in[12];
    const float* be2 = (const float*)d_in[13];
    const float* W21 = (const float*)d_in[14];
    const float* b21 = (const float*)d_in[15];
    const float* W22 = (const float*)d_in[16];
    const float* b22 = (const float*)d_in[17];
    const float* Wl1 = (const float*)d_in[18];
    const float* bl1 = (const float*)d_in[19];
    const float* Wl2 = (const float*)d_in[20];
    const float* bl2 = (const float*)d_in[21];
    float* out = (float*)d_out;

    char* ws = (char*)d_ws;
    const int* srcp = ei;
    const int* dstp = ei + Ee;

    // Barrier state must be clean before the kernel's first arrival.
    hipMemsetAsync(ws + OFF_BAR, 0, 256, stream);
    k_mega<<<NB, 256, 0, stream>>>(x, srcp, dstp, cur, des, nbr, ea,
                                   We1, be1, W11, b11, W12, b12,
                                   We2, be2, W21, b21, W22, b22,
                                   Wl1, bl1, Wl2, bl2, ws, out);
}

// Round 8
// 154.084 us; speedup vs baseline: 2.9896x; 2.9896x over previous
//
#include <hip/hip_runtime.h>

// Problem constants (fixed by the reference harness).
constexpr int Nn   = 100000;   // nodes
constexpr int Ee   = 1600000;  // edges  (divisible by 4)
constexpr int D    = 128;      // feature dim
constexpr int NT   = 18;       // 2 + 16 target entries (duplicates allowed)

// Capacities (expected: |L2|~290, |S|~330, conv1 hit edges ~5000)
constexpr int CAPS = 1024;
constexpr int CAP2 = 1024;

constexpr int BMW  = 3136;     // bitmap words: >= ceil(Nn/32)=3125, %4==0
constexpr int LOCT = 64;       // scanT per-block staging (expected ~0.6 hits)
constexpr int LOCS = 128;      // scanS per-block staging (expected ~10 hits)

// hdr slots
#define HDR_CNTS  1
#define HDR_CNTL2 3

// ---- workspace byte offsets (all 16B aligned) ----
constexpr size_t OFF_HDR   = 0;          // int[64]          256   (zeroed)
constexpr size_t OFF_MARKS = 256;        // int[Nn]          400000
constexpr size_t OFF_BMS   = 400256;     // u32[BMW]         12544
constexpr size_t OFF_A1    = 412800;     // f32[CAPS*D]      524288
constexpr size_t ZERO_BYTES= 937088;     // zero everything above (÷16 ok)
constexpr size_t OFF_SLIST = 937088;     // int[CAPS]        4096
constexpr size_t OFF_L2    = 941184;     // int[CAP2*3]      12288
constexpr size_t OFF_HS    = 953472;     // f32[CAPS*D]      524288
constexpr size_t WS_NEED   = 1477760;

__global__ void k_zero(float4* p, int n4) {
    int i = blockIdx.x * blockDim.x + threadIdx.x;
    int stride = gridDim.x * blockDim.x;
    for (; i < n4; i += stride) p[i] = float4{0.f, 0.f, 0.f, 0.f};
}

// Claim node v into the compact S set (markS: 0 -> 2+slot, -1 = claim sentinel).
// CAS makes claims unique under cross-block races; slot-counter atomics are
// ~330 total, spread across the scan.
__device__ __forceinline__ void claim_node(int v, int* markS, int* hdr,
                                           int* Slist, unsigned* bmS) {
    if (atomicCAS(&markS[v], 0, -1) == 0) {
        int s = atomicAdd(&hdr[HDR_CNTS], 1);
        if (s < CAPS) {
            Slist[s] = v;
            atomicOr(&bmS[(unsigned)v >> 5], 1u << (v & 31));
            markS[v] = 2 + s;   // plain store; next kernel boundary orders it
        }
    }
}

// Scan all edges; per-block LDS bitmap of the 18 target ids. Hits recorded
// into L2 (LDS-staged, one reservation atomic per block) and their sources
// claimed into S inline (stageC folded in). Block 0 claims the targets too.
__global__ void __launch_bounds__(256)
k_scanT(const int* __restrict__ src, const int* __restrict__ dst,
        const int* __restrict__ cur, const int* __restrict__ des,
        const int* __restrict__ nbr,
        int* __restrict__ hdr, int* __restrict__ markS,
        unsigned* __restrict__ bmS, int* __restrict__ Slist,
        int* __restrict__ L2) {
    __shared__ unsigned bm[BMW];
    __shared__ int sT[NT];
    __shared__ int loc[LOCT * 3];
    __shared__ int lcnt, lbase;
    int t = threadIdx.x;
    if (t == 0) lcnt = 0;
    for (int w = t; w < BMW; w += 256) bm[w] = 0u;
    if (t < NT) sT[t] = (t == 0) ? cur[0] : (t == 1) ? des[0] : nbr[t - 2];
    __syncthreads();
    if (t < NT) {
        int v = sT[t];
        atomicOr(&bm[(unsigned)v >> 5], 1u << (v & 31));
        if (blockIdx.x == 0) claim_node(v, markS, hdr, Slist, bmS);  // targets need h
    }
    __syncthreads();
    int stride = gridDim.x * blockDim.x;
    for (int q = blockIdx.x * blockDim.x + t; q < Ee / 4; q += stride) {
        int4 d4 = reinterpret_cast<const int4*>(dst)[q];
        int dsv[4] = {d4.x, d4.y, d4.z, d4.w};
        #pragma unroll
        for (int j = 0; j < 4; ++j) {
            int d = dsv[j];
            if ((bm[(unsigned)d >> 5] >> (d & 31)) & 1u) {
                int slot = 0;
                while (sT[slot] != d) ++slot;   // first occurrence, always found
                int e = q * 4 + j;
                int s = src[e];
                claim_node(s, markS, hdr, Slist, bmS);
                int li = atomicAdd(&lcnt, 1);
                if (li < LOCT) {
                    loc[3*li] = s; loc[3*li+1] = e; loc[3*li+2] = slot;
                } else {  // overflow fallback (statistically never)
                    int idx = atomicAdd(&hdr[HDR_CNTL2], 1);
                    if (idx < CAP2) { L2[3*idx] = s; L2[3*idx+1] = e; L2[3*idx+2] = slot; }
                }
            }
        }
    }
    __syncthreads();
    if (t == 0) {
        int n = lcnt < LOCT ? lcnt : LOCT;
        lcnt = n;
        if (n) lbase = atomicAdd(&hdr[HDR_CNTL2], n);
    }
    __syncthreads();
    for (int i = t; i < lcnt; i += 256) {
        int idx = lbase + i;
        if (idx < CAP2) {
            L2[3*idx] = loc[3*i]; L2[3*idx+1] = loc[3*i+1]; L2[3*idx+2] = loc[3*i+2];
        }
    }
}

// Scan all edges; membership test against LDS copy of S-bitmap; staged hits
// are aggregated cooperatively into A1 at the end (aggr1 folded in — no list).
// A1[slot][d] += relu(x[src][d] + ea[e]*We1[d] + be1[d])
__global__ void __launch_bounds__(256)
k_scanSA(const float* __restrict__ x, const int* __restrict__ src,
         const int* __restrict__ dst, const float* __restrict__ ea,
         const float* __restrict__ We1, const float* __restrict__ be1,
         const int* __restrict__ markS, const unsigned* __restrict__ bmS,
         float* __restrict__ A1) {
    __shared__ unsigned bm[BMW];
    __shared__ int loc[LOCS * 3];
    __shared__ int lcnt;
    int t = threadIdx.x;
    if (t == 0) lcnt = 0;
    const uint4* g4 = reinterpret_cast<const uint4*>(bmS);
    for (int w = t; w < BMW / 4; w += 256) reinterpret_cast<uint4*>(bm)[w] = g4[w];
    __syncthreads();
    int stride = gridDim.x * blockDim.x;
    for (int q = blockIdx.x * blockDim.x + t; q < Ee / 4; q += stride) {
        int4 d4 = reinterpret_cast<const int4*>(dst)[q];
        int dsv[4] = {d4.x, d4.y, d4.z, d4.w};
        #pragma unroll
        for (int j = 0; j < 4; ++j) {
            int d = dsv[j];
            if ((bm[(unsigned)d >> 5] >> (d & 31)) & 1u) {
                int v = markS[d];
                if (v >= 2) {
                    int e = q * 4 + j;
                    int li = atomicAdd(&lcnt, 1);
                    if (li < LOCS) {
                        loc[3*li] = src[e]; loc[3*li+1] = e; loc[3*li+2] = v - 2;
                    } else {  // inline slow path (statistically never)
                        float a = ea[e];
                        int s = src[e];
                        for (int d0 = 0; d0 < D; ++d0)
                            atomicAdd(&A1[(size_t)(v - 2) * D + d0],
                                      fmaxf(fmaf(a, We1[d0], be1[d0]) + x[(size_t)s * D + d0], 0.f));
                    }
                }
            }
        }
    }
    __syncthreads();
    int n = lcnt < LOCS ? lcnt : LOCS;
    int w = t >> 6, l = t & 63;          // 4 waves; lane handles 2 dims
    int d0 = l * 2;
    for (int i = w; i < n; i += 4) {
        int s = loc[3*i], e = loc[3*i+1], slot = loc[3*i+2];
        float a = ea[e];
        float2 xv = *reinterpret_cast<const float2*>(&x[(size_t)s * D + d0]);
        float2 wv = *reinterpret_cast<const float2*>(&We1[d0]);
        float2 bv = *reinterpret_cast<const float2*>(&be1[d0]);
        atomicAdd(&A1[(size_t)slot * D + d0],     fmaxf(fmaf(a, wv.x, bv.x) + xv.x, 0.f));
        atomicAdd(&A1[(size_t)slot * D + d0 + 1], fmaxf(fmaf(a, wv.y, bv.y) + xv.y, 0.f));
    }
}

// conv1 MLP per S-node: Hs[b] = relu( relu((x[node]+A1[b])@W1 + b1) @ W2 + b2 )
__global__ void k_mlpS(const float* __restrict__ x, const float* __restrict__ A,
                       const int* __restrict__ Slist, const int* __restrict__ hdr,
                       const float* __restrict__ W1, const float* __restrict__ b1,
                       const float* __restrict__ W2, const float* __restrict__ b2,
                       float* __restrict__ Hs) {
    __shared__ float buf[D];
    __shared__ float hid[D];
    int b = blockIdx.x;
    int cnt = hdr[HDR_CNTS];
    if (cnt > CAPS) cnt = CAPS;
    if (b >= cnt) return;
    int t = threadIdx.x;  // 128 threads
    int node = Slist[b];
    buf[t] = x[(size_t)node * D + t] + A[(size_t)b * D + t];
    __syncthreads();
    float acc = b1[t];
    #pragma unroll 8
    for (int k = 0; k < D; ++k) acc = fmaf(buf[k], W1[k * D + t], acc);
    hid[t] = fmaxf(acc, 0.f);
    __syncthreads();
    float acc2 = b2[t];
    #pragma unroll 8
    for (int k = 0; k < D; ++k) acc2 = fmaf(hid[k], W2[k * D + t], acc2);
    Hs[(size_t)b * D + t] = fmaxf(acc2, 0.f);
}

// Tail: single block fuses aggr2 (L2 edges -> LDS A2), conv2 MLP for the 18
// targets (-> LDS EMB), and the policy head (-> out[16]).
__global__ void __launch_bounds__(1024)
k_tail(const float* __restrict__ Hs, const int* __restrict__ L2,
       const int* __restrict__ hdr, const int* __restrict__ markS,
       const int* __restrict__ cur, const int* __restrict__ des,
       const int* __restrict__ nbr, const float* __restrict__ ea,
       const float* __restrict__ We2, const float* __restrict__ be2,
       const float* __restrict__ W21, const float* __restrict__ b21,
       const float* __restrict__ W22, const float* __restrict__ b22,
       const float* __restrict__ Wl1, const float* __restrict__ bl1,
       const float* __restrict__ Wl2, const float* __restrict__ bl2,
       float* __restrict__ out) {
    __shared__ float A2f[NT * D];    // 9216 B
    __shared__ float EMBl[NT * D];   // 9216 B
    __shared__ float buf[8][D];      // 4096 B
    __shared__ float hid[8][D];      // 4096 B
    __shared__ int sT[NT];
    int t = threadIdx.x;
    if (t < NT) sT[t] = (t == 0) ? cur[0] : (t == 1) ? des[0] : nbr[t - 2];
    for (int i = t; i < NT * D; i += 1024) A2f[i] = 0.f;
    __syncthreads();

    // ---- stage 1: aggregate conv2 messages into LDS A2 ----
    {
        int cnt2 = hdr[HDR_CNTL2]; if (cnt2 > CAP2) cnt2 = CAP2;
        int w = t >> 6, l = t & 63, d0 = l * 2;   // 16 waves, 2 dims/lane
        for (int i = w; i < cnt2; i += 16) {
            int s = L2[3*i], e = L2[3*i+1], slot = L2[3*i+2];
            int ss = markS[s] - 2;
            if ((unsigned)ss < (unsigned)CAPS) {
                float a = ea[e];
                float2 xv = *reinterpret_cast<const float2*>(&Hs[(size_t)ss * D + d0]);
                float2 wv = *reinterpret_cast<const float2*>(&We2[d0]);
                float2 bv = *reinterpret_cast<const float2*>(&be2[d0]);
                atomicAdd(&A2f[slot * D + d0],     fmaxf(fmaf(a, wv.x, bv.x) + xv.x, 0.f));
                atomicAdd(&A2f[slot * D + d0 + 1], fmaxf(fmaf(a, wv.y, bv.y) + xv.y, 0.f));
            }
        }
    }
    __syncthreads();

    // ---- stage 2: conv2 MLP for 18 targets (first occurrence only) ----
    {
        int g = t >> 7, tt = t & 127;   // 8 groups x 128 threads, 3 rounds
        for (int r = 0; r < 3; ++r) {
            int tgt = r * 8 + g;
            bool act = (tgt < NT);
            int ss = -1;
            if (act) {
                int node = sT[tgt];
                for (int j = 0; j < tgt; ++j) if (sT[j] == node) { act = false; break; }
                if (act) { ss = markS[node] - 2; if ((unsigned)ss >= (unsigned)CAPS) act = false; }
            }
            if (act) buf[g][tt] = Hs[(size_t)ss * D + tt] + A2f[tgt * D + tt];
            __syncthreads();
            if (act) {
                float acc = b21[tt];
                #pragma unroll 8
                for (int k = 0; k < D; ++k) acc = fmaf(buf[g][k], W21[k * D + tt], acc);
                hid[g][tt] = fmaxf(acc, 0.f);
            }
            __syncthreads();
            if (act) {
                float acc2 = b22[tt];
                #pragma unroll 8
                for (int k = 0; k < D; ++k) acc2 = fmaf(hid[g][k], W22[k * D + tt], acc2);
                EMBl[tgt * D + tt] = acc2;   // no final relu
            }
            __syncthreads();
        }
    }

    // ---- stage 3: policy head, one wave per neighbor k ----
    {
        int k = t >> 6, l = t & 63;     // 16 waves; lane handles 2 output dims
        int dsl = (sT[1] == sT[0]) ? 0 : 1;
        int nn = sT[2 + k];
        int nsl = 2 + k;
        for (int j = 0; j < 2 + k; ++j) if (sT[j] == nn) { nsl = j; break; }
        int o = l * 2;
        float acc0 = bl1[o], acc1 = bl1[o + 1];
        const float* e0 = &EMBl[0 * D];
        const float* e1 = &EMBl[dsl * D];
        const float* e2 = &EMBl[nsl * D];
        for (int c = 0; c < D; ++c) {
            float v = e0[c];   // broadcast LDS read
            acc0 = fmaf(v, Wl1[c * D + o], acc0);
            acc1 = fmaf(v, Wl1[c * D + o + 1], acc1);
        }
        for (int c = 0; c < D; ++c) {
            float v = e1[c];
            acc0 = fmaf(v, Wl1[(D + c) * D + o], acc0);
            acc1 = fmaf(v, Wl1[(D + c) * D + o + 1], acc1);
        }
        for (int c = 0; c < D; ++c) {
            float v = e2[c];
            acc0 = fmaf(v, Wl1[(2 * D + c) * D + o], acc0);
            acc1 = fmaf(v, Wl1[(2 * D + c) * D + o + 1], acc1);
        }
        float r = fmaxf(acc0, 0.f) * Wl2[o] + fmaxf(acc1, 0.f) * Wl2[o + 1];
        #pragma unroll
        for (int off = 32; off > 0; off >>= 1) r += __shfl_down(r, off);
        if (l == 0) out[k] = r + bl2[0];
    }
}

extern "C" void kernel_launch(void* const* d_in, const int* in_sizes, int n_in,
                              void* d_out, int out_size, void* d_ws, size_t ws_size,
                              hipStream_t stream) {
    if (ws_size < WS_NEED) return;  // safety guard

    const float* x   = (const float*)d_in[0];
    const int*   ei  = (const int*)d_in[1];   // (2,E) row-major int32
    const int*   cur = (const int*)d_in[2];
    const int*   des = (const int*)d_in[3];
    const int*   nbr = (const int*)d_in[4];
    const float* ea  = (const float*)d_in[5]; // (E,1)
    const float* We1 = (const float*)d_in[6];
    const float* be1 = (const float*)d_in[7];
    const float* W11 = (const float*)d_in[8];
    const float* b11 = (const float*)d_in[9];
    const float* W12 = (const float*)d_in[10];
    const float* b12 = (const float*)d_in[11];
    const float* We2 = (const float*)d_in[12];
    const float* be2 = (const float*)d_in[13];
    const float* W21 = (const float*)d_in[14];
    const float* b21 = (const float*)d_in[15];
    const float* W22 = (const float*)d_in[16];
    const float* b22 = (const float*)d_in[17];
    const float* Wl1 = (const float*)d_in[18];
    const float* bl1 = (const float*)d_in[19];
    const float* Wl2 = (const float*)d_in[20];
    const float* bl2 = (const float*)d_in[21];
    float* out = (float*)d_out;

    char*     ws    = (char*)d_ws;
    int*      hdr   = (int*)(ws + OFF_HDR);
    int*      markS = (int*)(ws + OFF_MARKS);
    unsigned* bmS   = (unsigned*)(ws + OFF_BMS);
    float*    A1    = (float*)(ws + OFF_A1);
    int*      Slist = (int*)(ws + OFF_SLIST);
    int*      L2    = (int*)(ws + OFF_L2);
    float*    Hs    = (float*)(ws + OFF_HS);

    const int* srcp = ei;
    const int* dstp = ei + Ee;

    k_zero  <<<256, 256, 0, stream>>>((float4*)ws, (int)(ZERO_BYTES / 16));
    k_scanT <<<512, 256, 0, stream>>>(srcp, dstp, cur, des, nbr,
                                      hdr, markS, bmS, Slist, L2);
    k_scanSA<<<512, 256, 0, stream>>>(x, srcp, dstp, ea, We1, be1,
                                      markS, bmS, A1);
    k_mlpS  <<<CAPS, 128, 0, stream>>>(x, A1, Slist, hdr, W11, b11, W12, b12, Hs);
    k_tail  <<<1, 1024, 0, stream>>>(Hs, L2, hdr, markS, cur, des, nbr, ea,
                                     We2, be2, W21, b21, W22, b22,
                                     Wl1, bl1, Wl2, bl2, out);
}

// Round 9
// 56.860 us; speedup vs baseline: 8.1014x; 2.7099x over previous
//
#include <hip/hip_runtime.h>

// Problem constants (fixed by the reference harness).
constexpr int Nn   = 100000;   // nodes
constexpr int Ee   = 1600000;  // edges  (divisible by 4)
constexpr int D    = 128;      // feature dim
constexpr int NT   = 18;       // 2 + 16 target entries (duplicates allowed)

// Capacities (expected: |L2|~290, |S|~350, conv1 hit edges ~5600)
constexpr int CAPS = 1024;
constexpr int CAP2 = 1024;

constexpr int BMW  = 3136;     // bitmap words: >= ceil(Nn/32)=3125, %4==0
constexpr int LOCT = 64;       // scanT per-block staging (expected ~0.6 hits)
constexpr int LOCS = 128;      // scanS per-block staging (expected ~11 hits)
constexpr int MAXM = 96;       // per-target matched-edge cap (mean ~16)

// hdr slots
#define HDR_CNTS  1
#define HDR_CNTL2 3

// ---- workspace byte offsets (all 16B aligned) ----
constexpr size_t OFF_HDR   = 0;          // int[64]          256   (zeroed)
constexpr size_t OFF_MARKS = 256;        // int[Nn]          400000
constexpr size_t OFF_BMS   = 400256;     // u32[BMW]         12544
constexpr size_t OFF_A1    = 412800;     // f32[CAPS*D]      524288
constexpr size_t ZERO_BYTES= 937088;     // zero everything above (÷16 ok)
constexpr size_t OFF_SLIST = 937088;     // int[CAPS]        4096
constexpr size_t OFF_L2    = 941184;     // int[CAP2*3]      12288
constexpr size_t OFF_HS    = 953472;     // f32[CAPS*D]      524288
constexpr size_t OFF_EMB   = 1477760;    // f32[NT*D]        9216
constexpr size_t WS_NEED   = 1486976;

__global__ void k_zero(float4* p, int n4) {
    int i = blockIdx.x * blockDim.x + threadIdx.x;
    int stride = gridDim.x * blockDim.x;
    for (; i < n4; i += stride) p[i] = float4{0.f, 0.f, 0.f, 0.f};
}

// Claim node v into the compact S set (markS: 0 -> 2+slot, -1 = claim sentinel).
// CAS makes claims unique under cross-block races; slot-counter atomics are
// ~350 total, spread across the scan.
__device__ __forceinline__ void claim_node(int v, int* markS, int* hdr,
                                           int* Slist, unsigned* bmS) {
    if (atomicCAS(&markS[v], 0, -1) == 0) {
        int s = atomicAdd(&hdr[HDR_CNTS], 1);
        if (s < CAPS) {
            Slist[s] = v;
            atomicOr(&bmS[(unsigned)v >> 5], 1u << (v & 31));
            markS[v] = 2 + s;   // plain store; next kernel boundary orders it
        }
    }
}

// Scan all edges; per-block LDS bitmap of the 18 target ids. Hits recorded
// into L2 (LDS-staged, one reservation atomic per block) and their sources
// claimed into S inline (stageC folded in). Block 0 claims the targets too.
__global__ void __launch_bounds__(256)
k_scanT(const int* __restrict__ src, const int* __restrict__ dst,
        const int* __restrict__ cur, const int* __restrict__ des,
        const int* __restrict__ nbr,
        int* __restrict__ hdr, int* __restrict__ markS,
        unsigned* __restrict__ bmS, int* __restrict__ Slist,
        int* __restrict__ L2) {
    __shared__ unsigned bm[BMW];
    __shared__ int sT[NT];
    __shared__ int loc[LOCT * 3];
    __shared__ int lcnt, lbase;
    int t = threadIdx.x;
    if (t == 0) lcnt = 0;
    for (int w = t; w < BMW; w += 256) bm[w] = 0u;
    if (t < NT) sT[t] = (t == 0) ? cur[0] : (t == 1) ? des[0] : nbr[t - 2];
    __syncthreads();
    if (t < NT) {
        int v = sT[t];
        atomicOr(&bm[(unsigned)v >> 5], 1u << (v & 31));
        if (blockIdx.x == 0) claim_node(v, markS, hdr, Slist, bmS);  // targets need h
    }
    __syncthreads();
    int stride = gridDim.x * blockDim.x;
    for (int q = blockIdx.x * blockDim.x + t; q < Ee / 4; q += stride) {
        int4 d4 = reinterpret_cast<const int4*>(dst)[q];
        int dsv[4] = {d4.x, d4.y, d4.z, d4.w};
        #pragma unroll
        for (int j = 0; j < 4; ++j) {
            int d = dsv[j];
            if ((bm[(unsigned)d >> 5] >> (d & 31)) & 1u) {
                int slot = 0;
                while (sT[slot] != d) ++slot;   // first occurrence, always found
                int e = q * 4 + j;
                int s = src[e];
                claim_node(s, markS, hdr, Slist, bmS);
                int li = atomicAdd(&lcnt, 1);
                if (li < LOCT) {
                    loc[3*li] = s; loc[3*li+1] = e; loc[3*li+2] = slot;
                } else {  // overflow fallback (statistically never)
                    int idx = atomicAdd(&hdr[HDR_CNTL2], 1);
                    if (idx < CAP2) { L2[3*idx] = s; L2[3*idx+1] = e; L2[3*idx+2] = slot; }
                }
            }
        }
    }
    __syncthreads();
    if (t == 0) {
        int n = lcnt < LOCT ? lcnt : LOCT;
        lcnt = n;
        if (n) lbase = atomicAdd(&hdr[HDR_CNTL2], n);
    }
    __syncthreads();
    for (int i = t; i < lcnt; i += 256) {
        int idx = lbase + i;
        if (idx < CAP2) {
            L2[3*idx] = loc[3*i]; L2[3*idx+1] = loc[3*i+1]; L2[3*idx+2] = loc[3*i+2];
        }
    }
}

// Scan all edges; membership test against LDS copy of S-bitmap; staged hits
// are aggregated cooperatively into A1 at the end (aggr1 folded in — no list).
// A1[slot][d] += relu(x[src][d] + ea[e]*We1[d] + be1[d])
__global__ void __launch_bounds__(256)
k_scanSA(const float* __restrict__ x, const int* __restrict__ src,
         const int* __restrict__ dst, const float* __restrict__ ea,
         const float* __restrict__ We1, const float* __restrict__ be1,
         const int* __restrict__ markS, const unsigned* __restrict__ bmS,
         float* __restrict__ A1) {
    __shared__ unsigned bm[BMW];
    __shared__ int loc[LOCS * 3];
    __shared__ int lcnt;
    int t = threadIdx.x;
    if (t == 0) lcnt = 0;
    const uint4* g4 = reinterpret_cast<const uint4*>(bmS);
    for (int w = t; w < BMW / 4; w += 256) reinterpret_cast<uint4*>(bm)[w] = g4[w];
    __syncthreads();
    int stride = gridDim.x * blockDim.x;
    for (int q = blockIdx.x * blockDim.x + t; q < Ee / 4; q += stride) {
        int4 d4 = reinterpret_cast<const int4*>(dst)[q];
        int dsv[4] = {d4.x, d4.y, d4.z, d4.w};
        #pragma unroll
        for (int j = 0; j < 4; ++j) {
            int d = dsv[j];
            if ((bm[(unsigned)d >> 5] >> (d & 31)) & 1u) {
                int v = markS[d];
                if (v >= 2) {
                    int e = q * 4 + j;
                    int li = atomicAdd(&lcnt, 1);
                    if (li < LOCS) {
                        loc[3*li] = src[e]; loc[3*li+1] = e; loc[3*li+2] = v - 2;
                    } else {  // inline slow path (statistically never)
                        float a = ea[e];
                        int s = src[e];
                        for (int d0 = 0; d0 < D; ++d0)
                            atomicAdd(&A1[(size_t)(v - 2) * D + d0],
                                      fmaxf(fmaf(a, We1[d0], be1[d0]) + x[(size_t)s * D + d0], 0.f));
                    }
                }
            }
        }
    }
    __syncthreads();
    int n = lcnt < LOCS ? lcnt : LOCS;
    int w = t >> 6, l = t & 63;          // 4 waves; lane handles 2 dims
    int d0 = l * 2;
    for (int i = w; i < n; i += 4) {
        int s = loc[3*i], e = loc[3*i+1], slot = loc[3*i+2];
        float a = ea[e];
        float2 xv = *reinterpret_cast<const float2*>(&x[(size_t)s * D + d0]);
        float2 wv = *reinterpret_cast<const float2*>(&We1[d0]);
        float2 bv = *reinterpret_cast<const float2*>(&be1[d0]);
        atomicAdd(&A1[(size_t)slot * D + d0],     fmaxf(fmaf(a, wv.x, bv.x) + xv.x, 0.f));
        atomicAdd(&A1[(size_t)slot * D + d0 + 1], fmaxf(fmaf(a, wv.y, bv.y) + xv.y, 0.f));
    }
}

// conv1 MLP per S-node: Hs[b] = relu( relu((x[node]+A1[b])@W1 + b1) @ W2 + b2 )
__global__ void k_mlpS(const float* __restrict__ x, const float* __restrict__ A,
                       const int* __restrict__ Slist, const int* __restrict__ hdr,
                       const float* __restrict__ W1, const float* __restrict__ b1,
                       const float* __restrict__ W2, const float* __restrict__ b2,
                       float* __restrict__ Hs) {
    __shared__ float buf[D];
    __shared__ float hid[D];
    int b = blockIdx.x;
    int cnt = hdr[HDR_CNTS];
    if (cnt > CAPS) cnt = CAPS;
    if (b >= cnt) return;
    int t = threadIdx.x;  // 128 threads
    int node = Slist[b];
    buf[t] = x[(size_t)node * D + t] + A[(size_t)b * D + t];
    __syncthreads();
    float acc = b1[t];
    #pragma unroll 8
    for (int k = 0; k < D; ++k) acc = fmaf(buf[k], W1[k * D + t], acc);
    hid[t] = fmaxf(acc, 0.f);
    __syncthreads();
    float acc2 = b2[t];
    #pragma unroll 8
    for (int k = 0; k < D; ++k) acc2 = fmaf(hid[k], W2[k * D + t], acc2);
    Hs[(size_t)b * D + t] = fmaxf(acc2, 0.f);
}

// Per-target tail: block b (0..17, first-occurrence only) filters the ~290
// L2 edges for slot==b, accumulates its conv2 aggregate in registers, then
// runs the conv2 MLP -> EMB[b]. 18 blocks spread over 18 CUs.
__global__ void __launch_bounds__(128)
k_tailT(const float* __restrict__ Hs, const int* __restrict__ L2,
        const int* __restrict__ hdr, const int* __restrict__ markS,
        const int* __restrict__ cur, const int* __restrict__ des,
        const int* __restrict__ nbr, const float* __restrict__ ea,
        const float* __restrict__ We2, const float* __restrict__ be2,
        const float* __restrict__ W21, const float* __restrict__ b21,
        const float* __restrict__ W22, const float* __restrict__ b22,
        float* __restrict__ EMB) {
    __shared__ int sT[NT];
    __shared__ float buf[D];
    __shared__ float hid[D];
    __shared__ int mss[MAXM];     // matched source slots
    __shared__ float mea[MAXM];   // matched edge attrs
    __shared__ int mcnt;
    int t = threadIdx.x;   // 128
    int b = blockIdx.x;    // 0..17
    if (t == 0) mcnt = 0;
    if (t < NT) sT[t] = (t == 0) ? cur[0] : (t == 1) ? des[0] : nbr[t - 2];
    __syncthreads();
    int node = sT[b];
    for (int j = 0; j < b; ++j) if (sT[j] == node) return;  // dup entry: skip
    int cnt2 = hdr[HDR_CNTL2]; if (cnt2 > CAP2) cnt2 = CAP2;
    for (int i = t; i < cnt2; i += 128) {
        if (L2[3*i + 2] == b) {
            int li = atomicAdd(&mcnt, 1);
            if (li < MAXM) {
                mss[li] = markS[L2[3*i]] - 2;
                mea[li] = ea[L2[3*i + 1]];
            }
        }
    }
    __syncthreads();
    int n = mcnt < MAXM ? mcnt : MAXM;
    float w2 = We2[t], bb2 = be2[t];
    float acc = 0.f;
    for (int i = 0; i < n; ++i) {
        int ss = mss[i];
        if ((unsigned)ss < (unsigned)CAPS)
            acc += fmaxf(fmaf(mea[i], w2, bb2) + Hs[(size_t)ss * D + t], 0.f);
    }
    int sst = markS[node] - 2;
    if ((unsigned)sst >= (unsigned)CAPS) return;
    buf[t] = Hs[(size_t)sst * D + t] + acc;
    __syncthreads();
    float a1 = b21[t];
    #pragma unroll 8
    for (int k = 0; k < D; ++k) a1 = fmaf(buf[k], W21[k * D + t], a1);
    hid[t] = fmaxf(a1, 0.f);
    __syncthreads();
    float a2 = b22[t];
    #pragma unroll 8
    for (int k = 0; k < D; ++k) a2 = fmaf(hid[k], W22[k * D + t], a2);
    EMB[b * D + t] = a2;   // no final relu
}

// Policy head: one block per neighbor k; 512 threads = 4-way split of the
// 384-long dot product, LDS-reduced. (Proven fast in R5.)
__global__ void __launch_bounds__(512)
k_policy(const float* __restrict__ EMB,
         const int* __restrict__ cur, const int* __restrict__ des,
         const int* __restrict__ nbr,
         const float* __restrict__ Wl1, const float* __restrict__ bl1,
         const float* __restrict__ Wl2, const float* __restrict__ bl2,
         float* __restrict__ out) {
    __shared__ int sT[NT];
    __shared__ float cat[3 * D];
    __shared__ float part[4][D];
    __shared__ float red[D];
    int tid = threadIdx.x;
    int k = blockIdx.x;  // 0..15
    if (tid < NT) sT[tid] = (tid == 0) ? cur[0] : (tid == 1) ? des[0] : nbr[tid - 2];
    __syncthreads();
    // first-occurrence slots (must match k_scanT / k_tailT semantics)
    int dsl = (sT[1] == sT[0]) ? 0 : 1;
    int nn = sT[2 + k];
    int nsl = 2 + k;
    for (int j = 0; j < 2 + k; ++j) if (sT[j] == nn) { nsl = j; break; }
    if (tid < 3 * D) {
        int seg = tid >> 7;             // 0=curr, 1=dest, 2=nbr
        int t = tid & (D - 1);
        int slot = (seg == 0) ? 0 : (seg == 1) ? dsl : nsl;
        cat[tid] = EMB[slot * D + t];
    }
    __syncthreads();
    int h = tid >> 7;        // 0..3
    int t = tid & (D - 1);
    float acc = 0.f;
    int c0 = h * 96;
    #pragma unroll 8
    for (int c = c0; c < c0 + 96; ++c)
        acc = fmaf(cat[c], Wl1[c * D + t], acc);
    part[h][t] = acc;
    __syncthreads();
    if (tid < D) {
        float v = part[0][t] + part[1][t] + part[2][t] + part[3][t] + bl1[t];
        red[t] = fmaxf(v, 0.f) * Wl2[t];
    }
    __syncthreads();
    for (int s = 64; s > 0; s >>= 1) {
        if (tid < s) red[tid] += red[tid + s];
        __syncthreads();
    }
    if (tid == 0) out[k] = red[0] + bl2[0];
}

extern "C" void kernel_launch(void* const* d_in, const int* in_sizes, int n_in,
                              void* d_out, int out_size, void* d_ws, size_t ws_size,
                              hipStream_t stream) {
    if (ws_size < WS_NEED) return;  // safety guard

    const float* x   = (const float*)d_in[0];
    const int*   ei  = (const int*)d_in[1];   // (2,E) row-major int32
    const int*   cur = (const int*)d_in[2];
    const int*   des = (const int*)d_in[3];
    const int*   nbr = (const int*)d_in[4];
    const float* ea  = (const float*)d_in[5]; // (E,1)
    const float* We1 = (const float*)d_in[6];
    const float* be1 = (const float*)d_in[7];
    const float* W11 = (const float*)d_in[8];
    const float* b11 = (const float*)d_in[9];
    const float* W12 = (const float*)d_in[10];
    const float* b12 = (const float*)d_in[11];
    const float* We2 = (const float*)d_in[12];
    const float* be2 = (const float*)d_in[13];
    const float* W21 = (const float*)d_in[14];
    const float* b21 = (const float*)d_in[15];
    const float* W22 = (const float*)d_in[16];
    const float* b22 = (const float*)d_in[17];
    const float* Wl1 = (const float*)d_in[18];
    const float* bl1 = (const float*)d_in[19];
    const float* Wl2 = (const float*)d_in[20];
    const float* bl2 = (const float*)d_in[21];
    float* out = (float*)d_out;

    char*     ws    = (char*)d_ws;
    int*      hdr   = (int*)(ws + OFF_HDR);
    int*      markS = (int*)(ws + OFF_MARKS);
    unsigned* bmS   = (unsigned*)(ws + OFF_BMS);
    float*    A1    = (float*)(ws + OFF_A1);
    int*      Slist = (int*)(ws + OFF_SLIST);
    int*      L2    = (int*)(ws + OFF_L2);
    float*    Hs    = (float*)(ws + OFF_HS);
    float*    EMB   = (float*)(ws + OFF_EMB);

    const int* srcp = ei;
    const int* dstp = ei + Ee;

    k_zero  <<<256, 256, 0, stream>>>((float4*)ws, (int)(ZERO_BYTES / 16));
    k_scanT <<<512, 256, 0, stream>>>(srcp, dstp, cur, des, nbr,
                                      hdr, markS, bmS, Slist, L2);
    k_scanSA<<<512, 256, 0, stream>>>(x, srcp, dstp, ea, We1, be1,
                                      markS, bmS, A1);
    k_mlpS  <<<CAPS, 128, 0, stream>>>(x, A1, Slist, hdr, W11, b11, W12, b12, Hs);
    k_tailT <<<NT, 128, 0, stream>>>(Hs, L2, hdr, markS, cur, des, nbr, ea,
                                     We2, be2, W21, b21, W22, b22, EMB);
    k_policy<<<16, 512, 0, stream>>>(EMB, cur, des, nbr, Wl1, bl1, Wl2, bl2, out);
}